// Round 6
// baseline (4275.803 us; speedup 1.0000x reference)
//
#include <hip/hip_runtime.h>
#include <math.h>

#define BATCH 16
#define TLEN 2048
#define NTOK (BATCH*TLEN)       // 32768
#define DMODEL 160
#define DINNER 320
#define DSTATE 64
#define DTRANK 10
#define XDBL 138                // DTRANK + 2*D_STATE
#define DCONV 12
#define PREK 9
#define NBLK 8

typedef __attribute__((ext_vector_type(8))) short short8;
typedef __attribute__((ext_vector_type(4))) float floatx4;

__device__ __forceinline__ float sigmoidf_(float x) { return 1.f / (1.f + __expf(-x)); }
__device__ __forceinline__ unsigned short f2bf(float f) {
  union { float f; unsigned u; } v; v.f = f;
  unsigned r = v.u + 0x7FFF + ((v.u >> 16) & 1);   // round-to-nearest-even
  return (unsigned short)(r >> 16);
}

// ---------------- pre conv (k=9, same pad) + exact GELU ----------------
__global__ __launch_bounds__(256)
void k_preconv(const float* __restrict__ x, const float* __restrict__ w,
               const float* __restrict__ bias, float* __restrict__ h) {
  int gid = blockIdx.x * 256 + threadIdx.x;
  if (gid >= NTOK * DMODEL) return;
  int c = gid % DMODEL;
  int tok = gid / DMODEL;
  int b = tok / TLEN, t = tok % TLEN;
  const float* xb = x + (size_t)b * TLEN;
  float acc = bias[c];
#pragma unroll
  for (int k = 0; k < PREK; ++k) {
    int tp = t + k - PREK / 2;
    float xv = (tp >= 0 && tp < TLEN) ? xb[tp] : 0.f;
    acc = fmaf(w[c * PREK + k], xv, acc);
  }
  h[gid] = 0.5f * acc * (1.f + erff(acc * 0.70710678118654752440f));
}

// ---------------- per-layer weight cast to bf16 ----------------
__global__ __launch_bounds__(256)
void k_cast(const float* __restrict__ iw, const float* __restrict__ xw,
            const float* __restrict__ ow, unsigned short* __restrict__ wbf) {
  int i = blockIdx.x * 256 + threadIdx.x;
  if (i < 102400) wbf[i] = f2bf(iw[i]);
  else if (i < 146560) wbf[i] = f2bf(xw[i - 102400]);
  else if (i < 197760) wbf[i] = f2bf(ow[i - 146560]);
}

// ---------------- LayerNorm over d=160 -> bf16 out ----------------
__global__ __launch_bounds__(256)
void k_ln(const float* __restrict__ h, const float* __restrict__ g,
          const float* __restrict__ bb, unsigned short* __restrict__ y) {
  int row = blockIdx.x * 4 + (threadIdx.x >> 6);
  int lane = threadIdx.x & 63;
  const float* hr = h + (size_t)row * DMODEL;
  float v0 = hr[lane], v1 = hr[lane + 64];
  float v2 = (lane < DMODEL - 128) ? hr[lane + 128] : 0.f;
  float s = v0 + v1 + v2;
  float sq = v0 * v0 + v1 * v1 + v2 * v2;
#pragma unroll
  for (int off = 32; off; off >>= 1) {
    s += __shfl_xor(s, off);
    sq += __shfl_xor(sq, off);
  }
  float mean = s * (1.f / DMODEL);
  float var = sq * (1.f / DMODEL) - mean * mean;
  float rstd = rsqrtf(var + 1e-5f);
  unsigned short* yr = y + (size_t)row * DMODEL;
  yr[lane] = f2bf((v0 - mean) * rstd * g[lane] + bb[lane]);
  yr[lane + 64] = f2bf((v1 - mean) * rstd * g[lane + 64] + bb[lane + 64]);
  if (lane < DMODEL - 128)
    yr[lane + 128] = f2bf((v2 - mean) * rstd * g[lane + 128] + bb[lane + 128]);
}

// ------- in_proj MFMA GEMM: A_bf[M,160] @ W_bf[640,160]^T -> xbuf/zbuf fp32 -------
__global__ __launch_bounds__(256)
void k_mm_in(const unsigned short* __restrict__ A, const unsigned short* __restrict__ Wb,
             float* __restrict__ xout, float* __restrict__ zout) {
  __shared__ short As[128 * 40];
  __shared__ short Ws[128 * 40];
  int tid = threadIdx.x;
  int m0 = blockIdx.y * 128, n0 = blockIdx.x * 128;
  int w = tid >> 6, lane = tid & 63;
  int rm = (w >> 1) * 64, cn = (w & 1) * 64;
  int lm = lane & 15, quad = lane >> 4;
  int r = tid >> 1, seg = tid & 1;     // row 0..127, 16-col half
  const unsigned short* pA = A + (size_t)(m0 + r) * DMODEL + seg * 16;
  const unsigned short* pW = Wb + (size_t)(n0 + r) * DMODEL + seg * 16;
  floatx4 acc[4][4];
#pragma unroll
  for (int i = 0; i < 4; ++i)
#pragma unroll
    for (int j = 0; j < 4; ++j)
      acc[i][j] = (floatx4){0.f, 0.f, 0.f, 0.f};
  for (int kt = 0; kt < 5; ++kt) {
    uint4 a0 = *(const uint4*)(pA + kt * 32);
    uint4 a1 = *(const uint4*)(pA + kt * 32 + 8);
    uint4 w0 = *(const uint4*)(pW + kt * 32);
    uint4 w1 = *(const uint4*)(pW + kt * 32 + 8);
    *(short8*)&As[r * 40 + seg * 16]     = *(short8*)&a0;
    *(short8*)&As[r * 40 + seg * 16 + 8] = *(short8*)&a1;
    *(short8*)&Ws[r * 40 + seg * 16]     = *(short8*)&w0;
    *(short8*)&Ws[r * 40 + seg * 16 + 8] = *(short8*)&w1;
    __syncthreads();
    short8 af[4], wf[4];
#pragma unroll
    for (int i = 0; i < 4; ++i)
      af[i] = *(short8*)&As[(rm + i * 16 + lm) * 40 + quad * 8];
#pragma unroll
    for (int j = 0; j < 4; ++j)
      wf[j] = *(short8*)&Ws[(cn + j * 16 + lm) * 40 + quad * 8];
#pragma unroll
    for (int i = 0; i < 4; ++i)
#pragma unroll
      for (int j = 0; j < 4; ++j)
        acc[i][j] = __builtin_amdgcn_mfma_f32_16x16x32_bf16(af[i], wf[j], acc[i][j], 0, 0, 0);
    __syncthreads();
  }
#pragma unroll
  for (int i = 0; i < 4; ++i)
#pragma unroll
    for (int reg = 0; reg < 4; ++reg) {
      int m = m0 + rm + i * 16 + quad * 4 + reg;
#pragma unroll
      for (int j = 0; j < 4; ++j) {
        int n = n0 + cn + j * 16 + lm;
        float v = acc[i][j][reg];
        if (n < DINNER) xout[(size_t)m * DINNER + n] = v;
        else zout[(size_t)m * DINNER + n - DINNER] = v;
      }
    }
}

// ------- generic MFMA GEMM: A_bf[M,K] @ W_bf[N,K]^T (+resid) -> C fp32 [M,N] -------
__global__ __launch_bounds__(256)
void k_mm_g(const unsigned short* __restrict__ A, const unsigned short* __restrict__ Wb,
            float* __restrict__ C, const float* __restrict__ resid, int N, int K) {
  __shared__ short As[128 * 40];
  __shared__ short Ws[64 * 40];
  int tid = threadIdx.x;
  int m0 = blockIdx.y * 128, n0 = blockIdx.x * 64;
  int w = tid >> 6, lane = tid & 63;
  int rm = w * 32;
  int lm = lane & 15, quad = lane >> 4;
  int r = tid >> 1, seg = tid & 1;     // A: row 0..127, 16-col half
  int wr = tid >> 2, wseg = tid & 3;   // W: row 0..63, 8-col quarter
  bool wvld = (n0 + wr) < N;
  const unsigned short* pA = A + (size_t)(m0 + r) * K + seg * 16;
  const unsigned short* pW = Wb + (size_t)(wvld ? (n0 + wr) : 0) * K + wseg * 8;
  floatx4 acc[2][4];
#pragma unroll
  for (int i = 0; i < 2; ++i)
#pragma unroll
    for (int j = 0; j < 4; ++j)
      acc[i][j] = (floatx4){0.f, 0.f, 0.f, 0.f};
  int nk = K >> 5;
  for (int kt = 0; kt < nk; ++kt) {
    uint4 a0 = *(const uint4*)(pA + kt * 32);
    uint4 a1 = *(const uint4*)(pA + kt * 32 + 8);
    uint4 wv = wvld ? *(const uint4*)(pW + kt * 32)
                    : make_uint4(0u, 0u, 0u, 0u);
    *(short8*)&As[r * 40 + seg * 16]     = *(short8*)&a0;
    *(short8*)&As[r * 40 + seg * 16 + 8] = *(short8*)&a1;
    *(short8*)&Ws[wr * 40 + wseg * 8]    = *(short8*)&wv;
    __syncthreads();
    short8 af[2], wf[4];
#pragma unroll
    for (int i = 0; i < 2; ++i)
      af[i] = *(short8*)&As[(rm + i * 16 + lm) * 40 + quad * 8];
#pragma unroll
    for (int j = 0; j < 4; ++j)
      wf[j] = *(short8*)&Ws[(j * 16 + lm) * 40 + quad * 8];
#pragma unroll
    for (int i = 0; i < 2; ++i)
#pragma unroll
      for (int j = 0; j < 4; ++j)
        acc[i][j] = __builtin_amdgcn_mfma_f32_16x16x32_bf16(af[i], wf[j], acc[i][j], 0, 0, 0);
    __syncthreads();
  }
#pragma unroll
  for (int i = 0; i < 2; ++i)
#pragma unroll
    for (int reg = 0; reg < 4; ++reg) {
      int m = m0 + rm + i * 16 + quad * 4 + reg;
#pragma unroll
      for (int j = 0; j < 4; ++j) {
        int n = n0 + j * 16 + lm;
        if (n < N) {
          float v = acc[i][j][reg];
          if (resid) v += resid[(size_t)m * N + n];
          C[(size_t)m * N + n] = v;
        }
      }
    }
}

// ---- depthwise causal conv (k=12) + SiLU: xbuf[tok][d] -> uT[b][d][t] fp32 + u_bf[tok][d] bf16 ----
__global__ __launch_bounds__(256)
void k_convT(const float* __restrict__ xbuf, const float* __restrict__ cw,
             const float* __restrict__ cb, float* __restrict__ uT,
             unsigned short* __restrict__ ubf) {
  int t0 = blockIdx.x * 64, d0 = blockIdx.y * 64, b = blockIdx.z;
  __shared__ float xs[76 * 65];
  __shared__ float us[64 * 65];
  int tid = threadIdx.x, j = tid & 63, w = tid >> 6;
#pragma unroll
  for (int it = 0; it < 19; ++it) {
    int r = it * 4 + w;                 // 0..75
    int t = t0 - (DCONV - 1) + r;
    xs[r * 65 + j] = (t >= 0 && t < TLEN)
        ? xbuf[((size_t)b * TLEN + t) * DINNER + d0 + j] : 0.f;
  }
  __syncthreads();
  float cwr[DCONV];
#pragma unroll
  for (int k = 0; k < DCONV; ++k) cwr[k] = cw[(d0 + j) * DCONV + k];
  float cbv = cb[d0 + j];
#pragma unroll
  for (int it = 0; it < 16; ++it) {
    int tl = it * 4 + w;                // 0..63
    float acc = cbv;
#pragma unroll
    for (int k = 0; k < DCONV; ++k)
      acc = fmaf(cwr[k], xs[(tl + k) * 65 + j], acc);
    us[tl * 65 + j] = acc * sigmoidf_(acc);
  }
  __syncthreads();
#pragma unroll
  for (int it = 0; it < 16; ++it) {
    int tr = it * 4 + w;
    ubf[((size_t)b * TLEN + t0 + tr) * DINNER + d0 + j] = f2bf(us[tr * 65 + j]);
  }
#pragma unroll
  for (int it = 0; it < 16; ++it) {
    int dl = it * 4 + w;
    uT[((size_t)b * DINNER + d0 + dl) * TLEN + t0 + j] = us[j * 65 + dl];
  }
}

// ---- pack: delT = softplus(dt@dtw^T + dtb) time-major; szT = silu(z) time-major ----
__global__ __launch_bounds__(256)
void k_pack(const float* __restrict__ zbuf, const float* __restrict__ xdbl,
            const float* __restrict__ dtw, const float* __restrict__ dtb,
            float* __restrict__ delT, float* __restrict__ szT) {
  int t0 = blockIdx.x * 64, d0 = blockIdx.y * 64, b = blockIdx.z;
  __shared__ float zs[64 * 65];
  __shared__ float xd[64 * 13];
  int tid = threadIdx.x, j = tid & 63, w = tid >> 6;
#pragma unroll
  for (int it = 0; it < 16; ++it) {
    int i = it * 4 + w;
    zs[i * 65 + j] = zbuf[((size_t)b * TLEN + t0 + i) * DINNER + d0 + j];
  }
  {
    int r = tid >> 2, c = tid & 3;
    size_t rowb = ((size_t)b * TLEN + t0 + r) * XDBL;
    for (int cc = c; cc < DTRANK; cc += 4)
      xd[r * 13 + cc] = xdbl[rowb + cc];
  }
  __syncthreads();
#pragma unroll
  for (int it = 0; it < 16; ++it) {
    int dl = it * 4 + w, d = d0 + dl;
    float acc = dtb[d];
    const float* wr = dtw + d * DTRANK;
#pragma unroll
    for (int rr = 0; rr < DTRANK; ++rr)
      acc = fmaf(xd[j * 13 + rr], wr[rr], acc);
    float del = (acc > 20.f) ? acc : log1pf(__expf(acc));
    size_t o = ((size_t)b * DINNER + d) * TLEN + t0 + j;
    delT[o] = del;
    float zv = zs[j * 65 + dl];
    szT[o] = zv * sigmoidf_(zv);
  }
}

// ---------------- selective scan: wave per (b,d), lane = state; batch-prefetched ----------------
// Per 16-t chunk: (1) load del/u (float4 x4 each, contiguous) + B/C (coalesced) into regs,
// (2) precompute dA=exp(del*Al) and x=del*u*B (independent of h), (3) serial fma chain,
// (4) deferred LDS reduction. Forces ~64 data VGPRs in flight to hide load latency.
__global__ __launch_bounds__(256)
void k_scan(const float* __restrict__ delT, const float* __restrict__ uT,
            const float* __restrict__ szT, const float* __restrict__ xdbl,
            const float* __restrict__ Alog, const float* __restrict__ Dskip,
            float* __restrict__ yT) {
  int wave = threadIdx.x >> 6, lane = threadIdx.x & 63;
  int b = blockIdx.x / (DINNER / 4);
  int d = (blockIdx.x % (DINNER / 4)) * 4 + wave;
  __shared__ float ps_all[4][16 * 65];
  float* ps = ps_all[wave];               // per-wave region; same-wave DS ops are ordered
  float Al = -__expf(Alog[d * DSTATE + lane]);
  float Dd = Dskip[d];
  size_t chan = ((size_t)b * DINNER + d) * TLEN;
  const float4* pd4 = (const float4*)(delT + chan);
  const float4* pu4 = (const float4*)(uT + chan);
  const float* pu  = uT + chan;
  const float* psz = szT + chan;
  float* py = yT + chan;
  const float* xb = xdbl + (size_t)b * TLEN * XDBL + DTRANK + lane;
  float h = 0.f;
  int tl = lane & 15, qq = lane >> 4;
  for (int c = 0; c < TLEN / 16; ++c) {
    int t0 = c * 16;
    // ---- phase 1: batch loads into registers ----
    float4 d4[4], u4[4];
#pragma unroll
    for (int i = 0; i < 4; ++i) { d4[i] = pd4[c * 4 + i]; u4[i] = pu4[c * 4 + i]; }
    float Bv[16], Cv[16];
#pragma unroll
    for (int t = 0; t < 16; ++t) {
      const float* xr = xb + (size_t)(t0 + t) * XDBL;
      Bv[t] = xr[0]; Cv[t] = xr[DSTATE];
    }
    float del[16], uu[16];
#pragma unroll
    for (int i = 0; i < 4; ++i) {
      del[i * 4 + 0] = d4[i].x; del[i * 4 + 1] = d4[i].y;
      del[i * 4 + 2] = d4[i].z; del[i * 4 + 3] = d4[i].w;
      uu[i * 4 + 0] = u4[i].x; uu[i * 4 + 1] = u4[i].y;
      uu[i * 4 + 2] = u4[i].z; uu[i * 4 + 3] = u4[i].w;
    }
    // ---- phase 2: independent work (exp pipeline, input products) ----
    float dA[16], xv[16];
#pragma unroll
    for (int t = 0; t < 16; ++t) dA[t] = __expf(del[t] * Al);
#pragma unroll
    for (int t = 0; t < 16; ++t) xv[t] = del[t] * uu[t] * Bv[t];
    // ---- phase 3: serial recurrence (one fma per t) ----
#pragma unroll
    for (int t = 0; t < 16; ++t) {
      h = fmaf(h, dA[t], xv[t]);
      ps[t * 65 + lane] = h * Cv[t];
    }
    // ---- phase 4: deferred reduction over states ----
    float p = 0.f;
#pragma unroll
    for (int i = 0; i < 16; ++i)
      p += ps[tl * 65 + qq * 16 + i];
    p += __shfl_xor(p, 16);
    p += __shfl_xor(p, 32);
    if (lane < 16) {
      int t = t0 + tl;
      py[t] = (p + pu[t] * Dd) * psz[t];
    }
  }
}

// ---- transpose yT[b][d][t] fp32 -> y_bf[tok][d] bf16 ----
__global__ __launch_bounds__(256)
void k_t2b(const float* __restrict__ yT, unsigned short* __restrict__ ybf) {
  int t0 = blockIdx.x * 64, d0 = blockIdx.y * 64, b = blockIdx.z;
  __shared__ float ls[64 * 65];
  int tid = threadIdx.x, j = tid & 63, w = tid >> 6;
#pragma unroll
  for (int it = 0; it < 16; ++it) {
    int dl = it * 4 + w;
    ls[dl * 65 + j] = yT[((size_t)b * DINNER + d0 + dl) * TLEN + t0 + j];
  }
  __syncthreads();
#pragma unroll
  for (int it = 0; it < 16; ++it) {
    int tr = it * 4 + w;
    ybf[((size_t)b * TLEN + t0 + tr) * DINNER + d0 + j] = f2bf(ls[j * 65 + tr]);
  }
}

// ---------------- head ----------------
__global__ __launch_bounds__(256)
void k_head(const float* __restrict__ h, const float* __restrict__ hw,
            const float* __restrict__ hb, float* __restrict__ out) {
  int tok = blockIdx.x * 4 + (threadIdx.x >> 6);
  int lane = threadIdx.x & 63;
  const float* hr = h + (size_t)tok * DMODEL;
  float s = hr[lane] * hw[lane] + hr[lane + 64] * hw[lane + 64];
  if (lane < DMODEL - 128) s += hr[lane + 128] * hw[lane + 128];
#pragma unroll
  for (int off = 32; off; off >>= 1) s += __shfl_xor(s, off);
  if (lane == 0) out[tok] = s + hb[0];
}

extern "C" void kernel_launch(void* const* d_in, const int* in_sizes, int n_in,
                              void* d_out, int out_size, void* d_ws, size_t ws_size,
                              hipStream_t stream) {
  const float* x      = (const float*)d_in[0];
  const float* pre_w  = (const float*)d_in[1];
  const float* pre_b  = (const float*)d_in[2];
  const float* ln_g   = (const float*)d_in[3];
  const float* ln_b   = (const float*)d_in[4];
  const float* in_w   = (const float*)d_in[5];
  const float* conv_w = (const float*)d_in[6];
  const float* conv_b = (const float*)d_in[7];
  const float* xproj_w= (const float*)d_in[8];
  const float* dt_w   = (const float*)d_in[9];
  const float* dt_b   = (const float*)d_in[10];
  const float* A_log  = (const float*)d_in[11];
  const float* D_skip = (const float*)d_in[12];
  const float* out_w  = (const float*)d_in[13];
  const float* head_w = (const float*)d_in[14];
  const float* head_b = (const float*)d_in[15];
  float* out = (float*)d_out;

  // workspace (floats), total 51,806,784 f = 207.2 MB:
  // h | xdbl | R (lnxd_bf -> u_bf -> delT, sequential lifetimes) |
  // xbuf (-> szT -> y_bf) | zbuf (-> yT) | uT | wbf
  float* ws   = (float*)d_ws;
  float* h    = ws;
  float* xdbl = h    + (size_t)NTOK * DMODEL;
  float* R    = xdbl + (size_t)NTOK * XDBL;
  float* xbuf = R    + (size_t)NTOK * DINNER;
  float* zbuf = xbuf + (size_t)NTOK * DINNER;
  float* uT   = zbuf + (size_t)NTOK * DINNER;
  unsigned short* wbf = (unsigned short*)(uT + (size_t)NTOK * DINNER);

  unsigned short* lnxd_bf = (unsigned short*)R;
  unsigned short* u_bf    = (unsigned short*)R;
  float*          delT    = R;
  float*          szT     = xbuf;
  unsigned short* y_bf    = (unsigned short*)xbuf;
  float*          yT      = zbuf;
  unsigned short* w_in    = wbf;
  unsigned short* w_xp    = wbf + 102400;
  unsigned short* w_ou    = wbf + 146560;

  k_preconv<<<NTOK * DMODEL / 256, 256, 0, stream>>>(x, pre_w, pre_b, h);

  for (int L = 0; L < NBLK; ++L) {
    k_cast<<<773, 256, 0, stream>>>(
        in_w + (size_t)L * 640 * DMODEL, xproj_w + (size_t)L * XDBL * DINNER,
        out_w + (size_t)L * DMODEL * DINNER, wbf);
    k_ln<<<NTOK / 4, 256, 0, stream>>>(h, ln_g + L * DMODEL, ln_b + L * DMODEL, lnxd_bf);
    k_mm_in<<<dim3(5, NTOK / 128), 256, 0, stream>>>(lnxd_bf, w_in, xbuf, zbuf);
    k_convT<<<dim3(TLEN / 64, DINNER / 64, BATCH), 256, 0, stream>>>(
        xbuf, conv_w + (size_t)L * DINNER * DCONV, conv_b + (size_t)L * DINNER, uT, u_bf);
    k_mm_g<<<dim3(3, NTOK / 128), 256, 0, stream>>>(u_bf, w_xp, xdbl, nullptr, XDBL, DINNER);
    k_pack<<<dim3(TLEN / 64, DINNER / 64, BATCH), 256, 0, stream>>>(
        zbuf, xdbl, dt_w + (size_t)L * DINNER * DTRANK, dt_b + (size_t)L * DINNER,
        delT, szT);
    k_scan<<<BATCH * (DINNER / 4), 256, 0, stream>>>(
        delT, uT, szT, xdbl, A_log + (size_t)L * DINNER * DSTATE,
        D_skip + (size_t)L * DINNER, yT);
    k_t2b<<<dim3(TLEN / 64, DINNER / 64, BATCH), 256, 0, stream>>>(yT, y_bf);
    k_mm_g<<<dim3(3, NTOK / 128), 256, 0, stream>>>(y_bf, w_ou, h, h, DMODEL, DINNER);
  }

  k_head<<<NTOK / 4, 256, 0, stream>>>(h, head_w, head_b, out);
}